// Round 1
// baseline (565.613 us; speedup 1.0000x reference)
//
#include <hip/hip_runtime.h>

// Triangle attention, B=1, I=J=256, C=128, H=4, Ch=32.
// Round 1: correct fp32-math implementation, bf16 intermediate storage.
// ws layout (bytes):
//   xn   bf16 [65536][128]        @ 0      (16 MB)
//   q    bf16 [I][H][J][32]       @ 16 MB
//   k    bf16 [I][H][J][32]       @ 32 MB
//   v    bf16 [I][H][J][32]       @ 48 MB
//   g    bf16 [65536][128]        @ 64 MB
//   o    bf16 [I][J][H][32]       @ 80 MB
//   triT f32  [H][256(k)][256(q)] @ 96 MB  (1 MB)  -- transposed for coalesced attn reads

#define NROWS 65536

__device__ __forceinline__ float bf2f(unsigned int u16) {
    return __uint_as_float(u16 << 16);
}
__device__ __forceinline__ unsigned int f2bf(float f) {
    unsigned int u = __float_as_uint(f);
    return (u + 0x7fffu + ((u >> 16) & 1u)) >> 16;
}
__device__ __forceinline__ unsigned int pack2(float a, float b) {
    return f2bf(a) | (f2bf(b) << 16);
}

// ---------------- Kernel 1: LayerNorm + tri bias -------------------------
// one wave per row (128 elems, 2 per lane); 4 waves per block
__global__ __launch_bounds__(256) void k_ln_tri(
    const float* __restrict__ x, const float* __restrict__ ln_w,
    const float* __restrict__ ln_b, const float* __restrict__ w_tri,
    unsigned int* __restrict__ xn_u32, float* __restrict__ triT)
{
    const int lane = threadIdx.x & 63;
    const int row  = blockIdx.x * 4 + (threadIdx.x >> 6);
    const float2 xv = ((const float2*)x)[row * 64 + lane];
    float s1 = xv.x + xv.y;
    float s2 = xv.x * xv.x + xv.y * xv.y;
    #pragma unroll
    for (int off = 32; off; off >>= 1) {
        s1 += __shfl_xor(s1, off);
        s2 += __shfl_xor(s2, off);
    }
    const float mu = s1 * (1.0f / 128.0f);
    const float rs = rsqrtf(s2 * (1.0f / 128.0f) - mu * mu + 1e-5f);
    const int c0 = lane * 2;
    const float xn0 = (xv.x - mu) * rs * ln_w[c0]     + ln_b[c0];
    const float xn1 = (xv.y - mu) * rs * ln_w[c0 + 1] + ln_b[c0 + 1];
    xn_u32[row * 64 + lane] = pack2(xn0, xn1);

    // tri partials: w_tri is [128][4] row-major -> float4 per c
    const float4 w0 = ((const float4*)w_tri)[c0];
    const float4 w1 = ((const float4*)w_tri)[c0 + 1];
    float px = xn0 * w0.x + xn1 * w1.x;
    float py = xn0 * w0.y + xn1 * w1.y;
    float pz = xn0 * w0.z + xn1 * w1.z;
    float pw = xn0 * w0.w + xn1 * w1.w;
    #pragma unroll
    for (int off = 32; off; off >>= 1) {
        px += __shfl_xor(px, off);
        py += __shfl_xor(py, off);
        pz += __shfl_xor(pz, off);
        pw += __shfl_xor(pw, off);
    }
    if (lane == 0) {
        const int i = row >> 8, j = row & 255;
        // bias[h][q=i_grid][k=j_grid] stored transposed: triT[h][j][i]
        triT[0 * 65536 + j * 256 + i] = px;
        triT[1 * 65536 + j * 256 + i] = py;
        triT[2 * 65536 + j * 256 + i] = pz;
        triT[3 * 65536 + j * 256 + i] = pw;
    }
}

// ---------------- Kernel 2: projections q,k,v,g --------------------------
// GEMM [65536 x 128] @ [128 x 128], blockIdx.y selects the weight matrix.
// BM=128, BN=128, KC=32; 256 threads, 8x8 micro-tile per thread.
__global__ __launch_bounds__(256) void k_proj(
    const unsigned short* __restrict__ xn,
    const float* __restrict__ wq, const float* __restrict__ wk,
    const float* __restrict__ wv, const float* __restrict__ wg,
    const float* __restrict__ bg,
    unsigned short* __restrict__ qb, unsigned short* __restrict__ kb,
    unsigned short* __restrict__ vb, unsigned short* __restrict__ gb)
{
    __shared__ float As[32 * 132];  // [k][m], padded
    __shared__ float Bs[32 * 132];  // [k][n], padded
    const int t = threadIdx.x;
    const int ty = t >> 4, tx = t & 15;
    const int rowBase = blockIdx.x * 128;
    const int mat = blockIdx.y;
    const float* W = (mat == 0) ? wq : (mat == 1) ? wk : (mat == 2) ? wv : wg;

    float acc[8][8];
    #pragma unroll
    for (int m = 0; m < 8; ++m)
        #pragma unroll
        for (int n = 0; n < 8; ++n) acc[m][n] = 0.0f;

    const int aRow = t >> 1;        // 0..127
    const int aK   = (t & 1) * 16;  // 0 / 16
    const int bK   = t >> 3;        // 0..31
    const int bC   = (t & 7) * 16;  // 0..112

    for (int kc = 0; kc < 128; kc += 32) {
        // stage A (xn tile, bf16 -> f32), layout [k][m]
        const uint4* asrc = (const uint4*)(xn + (size_t)(rowBase + aRow) * 128 + kc + aK);
        uint4 a0 = asrc[0], a1 = asrc[1];
        unsigned int aw[8] = {a0.x, a0.y, a0.z, a0.w, a1.x, a1.y, a1.z, a1.w};
        #pragma unroll
        for (int u = 0; u < 8; ++u) {
            As[(aK + 2 * u)     * 132 + aRow] = bf2f(aw[u] & 0xffffu);
            As[(aK + 2 * u + 1) * 132 + aRow] = bf2f(aw[u] >> 16);
        }
        // stage B (weights, f32)
        const float4* bsrc = (const float4*)(W + (size_t)(kc + bK) * 128 + bC);
        #pragma unroll
        for (int u = 0; u < 4; ++u)
            *(float4*)&Bs[bK * 132 + bC + 4 * u] = bsrc[u];
        __syncthreads();

        #pragma unroll 4
        for (int kk = 0; kk < 32; ++kk) {
            float a[8], b[8];
            *(float4*)&a[0] = *(const float4*)&As[kk * 132 + ty * 8];
            *(float4*)&a[4] = *(const float4*)&As[kk * 132 + ty * 8 + 4];
            *(float4*)&b[0] = *(const float4*)&Bs[kk * 132 + tx * 8];
            *(float4*)&b[4] = *(const float4*)&Bs[kk * 132 + tx * 8 + 4];
            #pragma unroll
            for (int m = 0; m < 8; ++m)
                #pragma unroll
                for (int n = 0; n < 8; ++n)
                    acc[m][n] += a[m] * b[n];
        }
        __syncthreads();
    }

    if (mat < 3) {
        unsigned short* dst = (mat == 0) ? qb : (mat == 1) ? kb : vb;
        const float scl = (mat == 0) ? 0.17677669529663689f : 1.0f;  // Ch^-0.5 on q
        const int h = tx >> 2, ch0 = (tx & 3) * 8;
        #pragma unroll
        for (int m = 0; m < 8; ++m) {
            const int r = rowBase + ty * 8 + m;
            const int i = r >> 8, j = r & 255;
            const size_t idx = (((size_t)i * 4 + h) * 256 + j) * 32 + ch0;
            uint4 pk;
            pk.x = pack2(acc[m][0] * scl, acc[m][1] * scl);
            pk.y = pack2(acc[m][2] * scl, acc[m][3] * scl);
            pk.z = pack2(acc[m][4] * scl, acc[m][5] * scl);
            pk.w = pack2(acc[m][6] * scl, acc[m][7] * scl);
            *(uint4*)(dst + idx) = pk;
        }
    } else {
        #pragma unroll
        for (int m = 0; m < 8; ++m) {
            const int r = rowBase + ty * 8 + m;
            float gv[8];
            #pragma unroll
            for (int n = 0; n < 8; ++n) {
                const float z = acc[m][n] + bg[tx * 8 + n];
                gv[n] = 1.0f / (1.0f + __expf(-z));
            }
            uint4 pk;
            pk.x = pack2(gv[0], gv[1]);
            pk.y = pack2(gv[2], gv[3]);
            pk.z = pack2(gv[4], gv[5]);
            pk.w = pack2(gv[6], gv[7]);
            *(uint4*)(gb + (size_t)r * 128 + tx * 8) = pk;
        }
    }
}

// ---------------- Kernel 3: attention per (i, h) --------------------------
// 128 threads; each thread owns q-rows {2t, 2t+1}; online softmax, chunk=8.
__global__ __launch_bounds__(128) void k_attn(
    const unsigned short* __restrict__ qb, const unsigned short* __restrict__ kb,
    const unsigned short* __restrict__ vb, const float* __restrict__ mask,
    const float* __restrict__ triT, unsigned short* __restrict__ ob)
{
    __shared__ float sK[256 * 36];
    __shared__ float sV[256 * 36];
    __shared__ float sM[256];
    const int i = blockIdx.x, h = blockIdx.y, t = threadIdx.x;
    const size_t base = ((size_t)(i * 4 + h)) * 256 * 32;

    // stage K, V (bf16 -> f32 into LDS), mask bias
    #pragma unroll
    for (int rr = 0; rr < 2; ++rr) {
        const int kk = t + rr * 128;
        const uint4* ks = (const uint4*)(kb + base + (size_t)kk * 32);
        const uint4* vs = (const uint4*)(vb + base + (size_t)kk * 32);
        #pragma unroll
        for (int u = 0; u < 4; ++u) {
            uint4 w = ks[u];
            float4 f0 = make_float4(bf2f(w.x & 0xffffu), bf2f(w.x >> 16),
                                    bf2f(w.y & 0xffffu), bf2f(w.y >> 16));
            float4 f1 = make_float4(bf2f(w.z & 0xffffu), bf2f(w.z >> 16),
                                    bf2f(w.w & 0xffffu), bf2f(w.w >> 16));
            *(float4*)&sK[kk * 36 + u * 8]     = f0;
            *(float4*)&sK[kk * 36 + u * 8 + 4] = f1;
            w = vs[u];
            f0 = make_float4(bf2f(w.x & 0xffffu), bf2f(w.x >> 16),
                             bf2f(w.y & 0xffffu), bf2f(w.y >> 16));
            f1 = make_float4(bf2f(w.z & 0xffffu), bf2f(w.z >> 16),
                             bf2f(w.w & 0xffffu), bf2f(w.w >> 16));
            *(float4*)&sV[kk * 36 + u * 8]     = f0;
            *(float4*)&sV[kk * 36 + u * 8 + 4] = f1;
        }
        sM[kk] = 1.0e9f * (mask[i * 256 + kk] - 1.0f);
    }

    // load this thread's two q rows
    float q0r[32], q1r[32];
    {
        const uint4* qs = (const uint4*)(qb + base + (size_t)(2 * t) * 32);
        #pragma unroll
        for (int u = 0; u < 4; ++u) {
            uint4 w = qs[u];
            q0r[u*8+0]=bf2f(w.x&0xffffu); q0r[u*8+1]=bf2f(w.x>>16);
            q0r[u*8+2]=bf2f(w.y&0xffffu); q0r[u*8+3]=bf2f(w.y>>16);
            q0r[u*8+4]=bf2f(w.z&0xffffu); q0r[u*8+5]=bf2f(w.z>>16);
            q0r[u*8+6]=bf2f(w.w&0xffffu); q0r[u*8+7]=bf2f(w.w>>16);
            w = qs[u + 4];
            q1r[u*8+0]=bf2f(w.x&0xffffu); q1r[u*8+1]=bf2f(w.x>>16);
            q1r[u*8+2]=bf2f(w.y&0xffffu); q1r[u*8+3]=bf2f(w.y>>16);
            q1r[u*8+4]=bf2f(w.z&0xffffu); q1r[u*8+5]=bf2f(w.z>>16);
            q1r[u*8+6]=bf2f(w.w&0xffffu); q1r[u*8+7]=bf2f(w.w>>16);
        }
    }
    __syncthreads();

    float m0 = -3.0e38f, m1 = -3.0e38f, l0 = 0.0f, l1 = 0.0f;
    float acc0[32], acc1[32];
    #pragma unroll
    for (int c = 0; c < 32; ++c) { acc0[c] = 0.0f; acc1[c] = 0.0f; }

    const float* triH = triT + h * 65536 + 2 * t;

    for (int kk0 = 0; kk0 < 256; kk0 += 8) {
        float s0[8], s1[8];
        #pragma unroll
        for (int jj = 0; jj < 8; ++jj) {
            const int kk = kk0 + jj;
            const float* Kr = &sK[kk * 36];
            float d0 = 0.0f, d1 = 0.0f;
            #pragma unroll
            for (int c = 0; c < 32; c += 4) {
                const float4 kv = *(const float4*)(Kr + c);
                d0 += q0r[c]*kv.x + q0r[c+1]*kv.y + q0r[c+2]*kv.z + q0r[c+3]*kv.w;
                d1 += q1r[c]*kv.x + q1r[c+1]*kv.y + q1r[c+2]*kv.z + q1r[c+3]*kv.w;
            }
            const float bias = sM[kk];
            const float2 tb = *(const float2*)(triH + kk * 256);
            s0[jj] = d0 + bias + tb.x;
            s1[jj] = d1 + bias + tb.y;
        }
        float c0 = s0[0], c1 = s1[0];
        #pragma unroll
        for (int jj = 1; jj < 8; ++jj) { c0 = fmaxf(c0, s0[jj]); c1 = fmaxf(c1, s1[jj]); }
        const float mn0 = fmaxf(m0, c0), mn1 = fmaxf(m1, c1);
        const float f0 = __expf(m0 - mn0), f1 = __expf(m1 - mn1);
        m0 = mn0; m1 = mn1;
        float p0[8], p1[8], sp0 = 0.0f, sp1 = 0.0f;
        #pragma unroll
        for (int jj = 0; jj < 8; ++jj) {
            p0[jj] = __expf(s0[jj] - mn0); sp0 += p0[jj];
            p1[jj] = __expf(s1[jj] - mn1); sp1 += p1[jj];
        }
        l0 = l0 * f0 + sp0;
        l1 = l1 * f1 + sp1;
        #pragma unroll
        for (int c = 0; c < 32; ++c) { acc0[c] *= f0; acc1[c] *= f1; }
        #pragma unroll
        for (int jj = 0; jj < 8; ++jj) {
            const float* Vr = &sV[(kk0 + jj) * 36];
            const float pj0 = p0[jj], pj1 = p1[jj];
            #pragma unroll
            for (int c = 0; c < 32; c += 4) {
                const float4 vv = *(const float4*)(Vr + c);
                acc0[c]   += pj0 * vv.x; acc0[c+1] += pj0 * vv.y;
                acc0[c+2] += pj0 * vv.z; acc0[c+3] += pj0 * vv.w;
                acc1[c]   += pj1 * vv.x; acc1[c+1] += pj1 * vv.y;
                acc1[c+2] += pj1 * vv.z; acc1[c+3] += pj1 * vv.w;
            }
        }
    }

    const float inv0 = 1.0f / l0, inv1 = 1.0f / l1;
    // o layout [i][j][h][ch]
    const size_t o0 = (((size_t)(i * 256 + 2 * t)) * 4 + h) * 32;
    const size_t o1 = o0 + 128;
    #pragma unroll
    for (int u = 0; u < 4; ++u) {
        uint4 pk;
        pk.x = pack2(acc0[u*8+0]*inv0, acc0[u*8+1]*inv0);
        pk.y = pack2(acc0[u*8+2]*inv0, acc0[u*8+3]*inv0);
        pk.z = pack2(acc0[u*8+4]*inv0, acc0[u*8+5]*inv0);
        pk.w = pack2(acc0[u*8+6]*inv0, acc0[u*8+7]*inv0);
        *(uint4*)(ob + o0 + u * 8) = pk;
        pk.x = pack2(acc1[u*8+0]*inv1, acc1[u*8+1]*inv1);
        pk.y = pack2(acc1[u*8+2]*inv1, acc1[u*8+3]*inv1);
        pk.z = pack2(acc1[u*8+4]*inv1, acc1[u*8+5]*inv1);
        pk.w = pack2(acc1[u*8+6]*inv1, acc1[u*8+7]*inv1);
        *(uint4*)(ob + o1 + u * 8) = pk;
    }
}

// ---------------- Kernel 4: (o*g) @ wo + bo -------------------------------
__global__ __launch_bounds__(256) void k_out(
    const unsigned short* __restrict__ ob, const unsigned short* __restrict__ gb,
    const float* __restrict__ wo, const float* __restrict__ bo,
    float* __restrict__ out)
{
    __shared__ float As[32 * 132];
    __shared__ float Bs[32 * 132];
    const int t = threadIdx.x;
    const int ty = t >> 4, tx = t & 15;
    const int rowBase = blockIdx.x * 128;

    float acc[8][8];
    #pragma unroll
    for (int m = 0; m < 8; ++m)
        #pragma unroll
        for (int n = 0; n < 8; ++n) acc[m][n] = 0.0f;

    const int aRow = t >> 1;
    const int aK   = (t & 1) * 16;
    const int bK   = t >> 3;
    const int bC   = (t & 7) * 16;

    for (int kc = 0; kc < 128; kc += 32) {
        const uint4* osrc = (const uint4*)(ob + (size_t)(rowBase + aRow) * 128 + kc + aK);
        const uint4* gsrc = (const uint4*)(gb + (size_t)(rowBase + aRow) * 128 + kc + aK);
        uint4 o0 = osrc[0], o1 = osrc[1];
        uint4 g0 = gsrc[0], g1 = gsrc[1];
        unsigned int ow[8] = {o0.x, o0.y, o0.z, o0.w, o1.x, o1.y, o1.z, o1.w};
        unsigned int gw[8] = {g0.x, g0.y, g0.z, g0.w, g1.x, g1.y, g1.z, g1.w};
        #pragma unroll
        for (int u = 0; u < 8; ++u) {
            As[(aK + 2*u)     * 132 + aRow] = bf2f(ow[u] & 0xffffu) * bf2f(gw[u] & 0xffffu);
            As[(aK + 2*u + 1) * 132 + aRow] = bf2f(ow[u] >> 16)     * bf2f(gw[u] >> 16);
        }
        const float4* bsrc = (const float4*)(wo + (size_t)(kc + bK) * 128 + bC);
        #pragma unroll
        for (int u = 0; u < 4; ++u)
            *(float4*)&Bs[bK * 132 + bC + 4 * u] = bsrc[u];
        __syncthreads();

        #pragma unroll 4
        for (int kk = 0; kk < 32; ++kk) {
            float a[8], b[8];
            *(float4*)&a[0] = *(const float4*)&As[kk * 132 + ty * 8];
            *(float4*)&a[4] = *(const float4*)&As[kk * 132 + ty * 8 + 4];
            *(float4*)&b[0] = *(const float4*)&Bs[kk * 132 + tx * 8];
            *(float4*)&b[4] = *(const float4*)&Bs[kk * 132 + tx * 8 + 4];
            #pragma unroll
            for (int m = 0; m < 8; ++m)
                #pragma unroll
                for (int n = 0; n < 8; ++n)
                    acc[m][n] += a[m] * b[n];
        }
        __syncthreads();
    }

    #pragma unroll
    for (int m = 0; m < 8; ++m) {
        const int r = rowBase + ty * 8 + m;
        float4 r0, r1;
        r0.x = acc[m][0] + bo[tx*8+0]; r0.y = acc[m][1] + bo[tx*8+1];
        r0.z = acc[m][2] + bo[tx*8+2]; r0.w = acc[m][3] + bo[tx*8+3];
        r1.x = acc[m][4] + bo[tx*8+4]; r1.y = acc[m][5] + bo[tx*8+5];
        r1.z = acc[m][6] + bo[tx*8+6]; r1.w = acc[m][7] + bo[tx*8+7];
        *(float4*)(out + (size_t)r * 128 + tx * 8)     = r0;
        *(float4*)(out + (size_t)r * 128 + tx * 8 + 4) = r1;
    }
}

extern "C" void kernel_launch(void* const* d_in, const int* in_sizes, int n_in,
                              void* d_out, int out_size, void* d_ws, size_t ws_size,
                              hipStream_t stream) {
    (void)in_sizes; (void)n_in; (void)out_size; (void)ws_size;
    const float* x     = (const float*)d_in[0];
    const float* mask  = (const float*)d_in[1];
    const float* ln_w  = (const float*)d_in[2];
    const float* ln_b  = (const float*)d_in[3];
    const float* w_tri = (const float*)d_in[4];
    const float* wq    = (const float*)d_in[5];
    const float* wk    = (const float*)d_in[6];
    const float* wv    = (const float*)d_in[7];
    const float* wg    = (const float*)d_in[8];
    const float* bg    = (const float*)d_in[9];
    const float* wo    = (const float*)d_in[10];
    const float* bo    = (const float*)d_in[11];
    float* out = (float*)d_out;

    char* ws = (char*)d_ws;
    unsigned int*   xn_u32 = (unsigned int*)ws;                       // 16 MB
    unsigned short* xn     = (unsigned short*)ws;
    unsigned short* qb     = (unsigned short*)(ws + (16u << 20));
    unsigned short* kb     = (unsigned short*)(ws + (32u << 20));
    unsigned short* vb     = (unsigned short*)(ws + (48u << 20));
    unsigned short* gb     = (unsigned short*)(ws + (64u << 20));
    unsigned short* ob     = (unsigned short*)(ws + (80u << 20));
    float*          triT   = (float*)(ws + (96u << 20));              // 1 MB

    k_ln_tri<<<NROWS / 4, 256, 0, stream>>>(x, ln_w, ln_b, w_tri, xn_u32, triT);
    k_proj<<<dim3(512, 4), 256, 0, stream>>>(xn, wq, wk, wv, wg, bg, qb, kb, vb, gb);
    k_attn<<<dim3(256, 4), 128, 0, stream>>>(qb, kb, vb, mask, triT, ob);
    k_out<<<512, 256, 0, stream>>>(ob, gb, wo, bo, out);
}

// Round 2
// 161.740 us; speedup vs baseline: 3.4970x; 3.4970x over previous
//
#include <hip/hip_runtime.h>

// Triangle attention, B=1, I=J=256, C=128, H=4, Ch=32.
// Round 2: MFMA (16x16x32 bf16) for proj / attention / out GEMMs.
// ws layout (bytes):
//   xn    bf16 [65536][128]          @ 0
//   q     bf16 [I][H][J][32]         @ 16 MB
//   k     bf16 [I][H][J][32]         @ 32 MB
//   v     bf16 [I][H][J][32]         @ 48 MB
//   g     bf16 [65536][128]          @ 64 MB
//   o     bf16 [I][J][H][32]         @ 80 MB
//   triTb bf16 [H][256(k)][256(q)]   @ 96 MB        (512 KB)
//   wT    bf16 5 x [128(n)][128(k)]  @ 96 MB+512KB  (160 KB)  (wq,wk,wv,wg,wo transposed)

#define NROWS 65536

typedef __attribute__((ext_vector_type(4))) float f32x4;
typedef __attribute__((ext_vector_type(8))) short bf16x8;
#define MFMA16(a, b, c) __builtin_amdgcn_mfma_f32_16x16x32_bf16(a, b, c, 0, 0, 0)

__device__ __forceinline__ float bf2f(unsigned int u16) {
    return __uint_as_float(u16 << 16);
}
__device__ __forceinline__ unsigned int f2bf(float f) {
    unsigned int u = __float_as_uint(f);
    return (u + 0x7fffu + ((u >> 16) & 1u)) >> 16;
}
__device__ __forceinline__ unsigned int pack2(float a, float b) {
    return f2bf(a) | (f2bf(b) << 16);
}
__device__ __forceinline__ unsigned int cvt_pk_bf16(float lo, float hi) {
    unsigned int r;
    asm("v_cvt_pk_bf16_f32 %0, %1, %2" : "=v"(r) : "v"(lo), "v"(hi));
    return r;
}

// ---------------- Kernel 0: weight transpose + bf16 cast -----------------
// block (mat, kchunk): thread t owns output row n=t; reads W[k][t] coalesced.
__global__ __launch_bounds__(128) void k_prep(
    const float* __restrict__ wq, const float* __restrict__ wk,
    const float* __restrict__ wv, const float* __restrict__ wg,
    const float* __restrict__ wo, unsigned short* __restrict__ wT)
{
    const int mat = blockIdx.x, k0 = blockIdx.y * 16, t = threadIdx.x;
    const float* W = (mat == 0) ? wq : (mat == 1) ? wk : (mat == 2) ? wv
                     : (mat == 3) ? wg : wo;
    unsigned short* T = wT + mat * 16384;
    float col[16];
    #pragma unroll
    for (int kk = 0; kk < 16; ++kk) col[kk] = W[(k0 + kk) * 128 + t];
    unsigned int pk[8];
    #pragma unroll
    for (int u = 0; u < 8; ++u) pk[u] = pack2(col[2 * u], col[2 * u + 1]);
    *(uint4*)(T + t * 128 + k0)     = make_uint4(pk[0], pk[1], pk[2], pk[3]);
    *(uint4*)(T + t * 128 + k0 + 8) = make_uint4(pk[4], pk[5], pk[6], pk[7]);
}

// ---------------- Kernel 1: LayerNorm + tri bias -------------------------
__global__ __launch_bounds__(256) void k_ln_tri(
    const float* __restrict__ x, const float* __restrict__ ln_w,
    const float* __restrict__ ln_b, const float* __restrict__ w_tri,
    unsigned int* __restrict__ xn_u32, unsigned short* __restrict__ triTb)
{
    const int lane = threadIdx.x & 63;
    const int row  = blockIdx.x * 4 + (threadIdx.x >> 6);
    const float2 xv = ((const float2*)x)[row * 64 + lane];
    float s1 = xv.x + xv.y;
    float s2 = xv.x * xv.x + xv.y * xv.y;
    #pragma unroll
    for (int off = 32; off; off >>= 1) {
        s1 += __shfl_xor(s1, off);
        s2 += __shfl_xor(s2, off);
    }
    const float mu = s1 * (1.0f / 128.0f);
    const float rs = rsqrtf(s2 * (1.0f / 128.0f) - mu * mu + 1e-5f);
    const int c0 = lane * 2;
    const float xn0 = (xv.x - mu) * rs * ln_w[c0]     + ln_b[c0];
    const float xn1 = (xv.y - mu) * rs * ln_w[c0 + 1] + ln_b[c0 + 1];
    xn_u32[row * 64 + lane] = pack2(xn0, xn1);

    const float4 w0 = ((const float4*)w_tri)[c0];
    const float4 w1 = ((const float4*)w_tri)[c0 + 1];
    float px = xn0 * w0.x + xn1 * w1.x;
    float py = xn0 * w0.y + xn1 * w1.y;
    float pz = xn0 * w0.z + xn1 * w1.z;
    float pw = xn0 * w0.w + xn1 * w1.w;
    #pragma unroll
    for (int off = 32; off; off >>= 1) {
        px += __shfl_xor(px, off);
        py += __shfl_xor(py, off);
        pz += __shfl_xor(pz, off);
        pw += __shfl_xor(pw, off);
    }
    if (lane == 0) {
        const int i = row >> 8, j = row & 255;
        // bias[h][k=j][q=i]
        triTb[0 * 65536 + j * 256 + i] = (unsigned short)f2bf(px);
        triTb[1 * 65536 + j * 256 + i] = (unsigned short)f2bf(py);
        triTb[2 * 65536 + j * 256 + i] = (unsigned short)f2bf(pz);
        triTb[3 * 65536 + j * 256 + i] = (unsigned short)f2bf(pw);
    }
}

// ---------------- Kernel 2: projections q,k,v,g (MFMA) --------------------
// [65536 x 128] @ Wt^T. BM=128, N=128, K=128 fully staged. 4 waves.
__global__ __launch_bounds__(256, 2) void k_proj2(
    const unsigned short* __restrict__ xn, const unsigned short* __restrict__ wT,
    const float* __restrict__ bg,
    unsigned short* __restrict__ qb, unsigned short* __restrict__ kb,
    unsigned short* __restrict__ vb, unsigned short* __restrict__ gb)
{
    __shared__ unsigned short sA[128 * 136];
    __shared__ unsigned short sB[128 * 136];
    const int t = threadIdx.x, w = t >> 6, lane = t & 63;
    const int l15 = lane & 15, g = lane >> 4;
    const int rowBase = blockIdx.x * 128, mat = blockIdx.y;
    const unsigned short* Wm = wT + mat * 16384;

    {
        const int r = t >> 1, half = t & 1;
        #pragma unroll
        for (int u = 0; u < 8; ++u) {
            const int c = half * 64 + u * 8;
            *(uint4*)&sA[r * 136 + c] = *(const uint4*)(xn + (size_t)(rowBase + r) * 128 + c);
            *(uint4*)&sB[r * 136 + c] = *(const uint4*)(Wm + r * 128 + c);
        }
    }
    __syncthreads();

    f32x4 acc[2][8];
    #pragma unroll
    for (int m = 0; m < 2; ++m)
        #pragma unroll
        for (int n = 0; n < 8; ++n) acc[m][n] = (f32x4){0.f, 0.f, 0.f, 0.f};

    bf16x8 af[2][4];
    #pragma unroll
    for (int m = 0; m < 2; ++m)
        #pragma unroll
        for (int ks = 0; ks < 4; ++ks)
            af[m][ks] = *(const bf16x8*)&sA[(w * 32 + m * 16 + l15) * 136 + ks * 32 + g * 8];
    #pragma unroll
    for (int n = 0; n < 8; ++n) {
        #pragma unroll
        for (int ks = 0; ks < 4; ++ks) {
            const bf16x8 bf = *(const bf16x8*)&sB[(n * 16 + l15) * 136 + ks * 32 + g * 8];
            acc[0][n] = MFMA16(af[0][ks], bf, acc[0][n]);
            acc[1][n] = MFMA16(af[1][ks], bf, acc[1][n]);
        }
    }
    __syncthreads();

    // epilogue: activation + bf16 pack into sA, then coalesced stores
    float bgv[8];
    if (mat == 3) {
        #pragma unroll
        for (int n = 0; n < 8; ++n) bgv[n] = bg[n * 16 + l15];
    }
    const float scl = (mat == 0) ? 0.17677669529663689f : 1.0f;
    #pragma unroll
    for (int m = 0; m < 2; ++m) {
        #pragma unroll
        for (int n = 0; n < 8; ++n) {
            float v[4];
            #pragma unroll
            for (int reg = 0; reg < 4; ++reg) {
                float z = acc[m][n][reg];
                if (mat == 3) z = 1.0f / (1.0f + __expf(-(z + bgv[n])));
                else z *= scl;
                v[reg] = z;
            }
            const unsigned int a01 = cvt_pk_bf16(v[0], v[1]);
            const unsigned int a23 = cvt_pk_bf16(v[2], v[3]);
            const int qr = w * 32 + m * 16 + g * 4;
            const int col = n * 16 + l15;
            sA[qr * 136 + col]       = (unsigned short)a01;
            sA[(qr + 1) * 136 + col] = (unsigned short)(a01 >> 16);
            sA[(qr + 2) * 136 + col] = (unsigned short)a23;
            sA[(qr + 3) * 136 + col] = (unsigned short)(a23 >> 16);
        }
    }
    __syncthreads();

    const int r = t >> 1, half = t & 1;
    if (mat < 3) {
        unsigned short* dst = (mat == 0) ? qb : (mat == 1) ? kb : vb;
        const int row = rowBase + r, i = row >> 8, j = row & 255;
        #pragma unroll
        for (int u = 0; u < 8; ++u) {
            const int c0 = half * 64 + u * 8;
            const int h = c0 >> 5, ch = c0 & 31;
            *(uint4*)(dst + (((size_t)(i * 4 + h)) * 256 + j) * 32 + ch) =
                *(const uint4*)&sA[r * 136 + c0];
        }
    } else {
        #pragma unroll
        for (int u = 0; u < 8; ++u) {
            const int c0 = half * 64 + u * 8;
            *(uint4*)(gb + (size_t)(rowBase + r) * 128 + c0) = *(const uint4*)&sA[r * 136 + c0];
        }
    }
}

// ---------------- Kernel 3: flash attention per (i,h), MFMA ---------------
// 4 waves x 64 q-rows; kv-tiles of 64; P via per-wave LDS round-trip.
__global__ __launch_bounds__(256, 2) void k_attn2(
    const unsigned short* __restrict__ qb, const unsigned short* __restrict__ kb,
    const unsigned short* __restrict__ vb, const float* __restrict__ mask,
    const unsigned short* __restrict__ triTb, unsigned short* __restrict__ ob)
{
    __shared__ unsigned short sK[256 * 40];    // [kv][c] pad 40
    __shared__ unsigned short sVt[32 * 264];   // [c][kv] pad 264
    __shared__ unsigned short sP[4][64 * 72];  // per-wave [q][kv] pad 72
    __shared__ float sM[256];

    const int i = blockIdx.x, h = blockIdx.y, t = threadIdx.x;
    const int w = t >> 6, lane = t & 63, l15 = lane & 15, g = lane >> 4;
    const size_t base = (size_t)(i * 4 + h) * 8192;

    {
        const uint4* ks = (const uint4*)(kb + base + t * 32);
        uint4 k0 = ks[0], k1 = ks[1], k2 = ks[2], k3 = ks[3];
        *(uint4*)&sK[t * 40]      = k0;
        *(uint4*)&sK[t * 40 + 8]  = k1;
        *(uint4*)&sK[t * 40 + 16] = k2;
        *(uint4*)&sK[t * 40 + 24] = k3;
        const uint4* vs = (const uint4*)(vb + base + t * 32);
        uint4 v0 = vs[0], v1 = vs[1], v2 = vs[2], v3 = vs[3];
        const unsigned int vw[16] = {v0.x, v0.y, v0.z, v0.w, v1.x, v1.y, v1.z, v1.w,
                                     v2.x, v2.y, v2.z, v2.w, v3.x, v3.y, v3.z, v3.w};
        #pragma unroll
        for (int u = 0; u < 16; ++u) {
            sVt[(2 * u) * 264 + t]     = (unsigned short)(vw[u] & 0xffffu);
            sVt[(2 * u + 1) * 264 + t] = (unsigned short)(vw[u] >> 16);
        }
        sM[t] = 1.0e9f * (mask[i * 256 + t] - 1.0f);
    }
    const int q0 = w * 64;
    bf16x8 qf[4];
    #pragma unroll
    for (int m = 0; m < 4; ++m)
        qf[m] = *(const bf16x8*)(qb + base + (size_t)(q0 + m * 16 + l15) * 32 + g * 8);
    __syncthreads();

    f32x4 acc[4][2];
    float m_run[4][4], l_run[4][4];
    #pragma unroll
    for (int m = 0; m < 4; ++m) {
        acc[m][0] = (f32x4){0.f, 0.f, 0.f, 0.f};
        acc[m][1] = (f32x4){0.f, 0.f, 0.f, 0.f};
        #pragma unroll
        for (int r = 0; r < 4; ++r) { m_run[m][r] = -1.0e30f; l_run[m][r] = 0.0f; }
    }

    for (int kt = 0; kt < 4; ++kt) {
        const int kv0 = kt * 64;
        // tri bias prefetch: [h][kv][q], reg-contiguous in q
        ushort4 trv[4][4];
        #pragma unroll
        for (int n = 0; n < 4; ++n) {
            const unsigned short* tp = triTb + h * 65536 + (kv0 + n * 16 + l15) * 256;
            #pragma unroll
            for (int m = 0; m < 4; ++m)
                trv[m][n] = *(const ushort4*)(tp + q0 + m * 16 + g * 4);
        }
        float smv[4];
        #pragma unroll
        for (int n = 0; n < 4; ++n) smv[n] = sM[kv0 + n * 16 + l15];

        bf16x8 kf[4];
        #pragma unroll
        for (int n = 0; n < 4; ++n)
            kf[n] = *(const bf16x8*)&sK[(kv0 + n * 16 + l15) * 40 + g * 8];

        const f32x4 zero = {0.f, 0.f, 0.f, 0.f};
        f32x4 p[4][4];
        #pragma unroll
        for (int m = 0; m < 4; ++m)
            #pragma unroll
            for (int n = 0; n < 4; ++n)
                p[m][n] = MFMA16(qf[m], kf[n], zero);

        // online softmax: row = q0 + 16m + 4g + reg, col = kv0 + 16n + l15
        #pragma unroll
        for (int m = 0; m < 4; ++m) {
            float f[4];
            #pragma unroll
            for (int reg = 0; reg < 4; ++reg) {
                #pragma unroll
                for (int n = 0; n < 4; ++n)
                    p[m][n][reg] += smv[n] + bf2f(((const unsigned short*)&trv[m][n])[reg]);
                float mx = fmaxf(fmaxf(p[m][0][reg], p[m][1][reg]),
                                 fmaxf(p[m][2][reg], p[m][3][reg]));
                #pragma unroll
                for (int off = 1; off < 16; off <<= 1)
                    mx = fmaxf(mx, __shfl_xor(mx, off));
                const float mnew = fmaxf(m_run[m][reg], mx);
                f[reg] = __expf(m_run[m][reg] - mnew);
                m_run[m][reg] = mnew;
                float sum = 0.0f;
                #pragma unroll
                for (int n = 0; n < 4; ++n) {
                    p[m][n][reg] = __expf(p[m][n][reg] - mnew);
                    sum += p[m][n][reg];
                }
                #pragma unroll
                for (int off = 1; off < 16; off <<= 1)
                    sum += __shfl_xor(sum, off);
                l_run[m][reg] = l_run[m][reg] * f[reg] + sum;
            }
            #pragma unroll
            for (int n2 = 0; n2 < 2; ++n2)
                #pragma unroll
                for (int reg = 0; reg < 4; ++reg)
                    acc[m][n2][reg] *= f[reg];
            // pack P -> per-wave LDS [q][kv]
            #pragma unroll
            for (int n = 0; n < 4; ++n) {
                const unsigned int a01 = cvt_pk_bf16(p[m][n][0], p[m][n][1]);
                const unsigned int a23 = cvt_pk_bf16(p[m][n][2], p[m][n][3]);
                const int qr = m * 16 + g * 4;
                const int col = n * 16 + l15;
                sP[w][qr * 72 + col]       = (unsigned short)a01;
                sP[w][(qr + 1) * 72 + col] = (unsigned short)(a01 >> 16);
                sP[w][(qr + 2) * 72 + col] = (unsigned short)a23;
                sP[w][(qr + 3) * 72 + col] = (unsigned short)(a23 >> 16);
            }
        }
        __syncthreads();
        // PV: O += P[64x64] @ V[64x32]
        #pragma unroll
        for (int ks = 0; ks < 2; ++ks) {
            bf16x8 vf[2];
            #pragma unroll
            for (int n2 = 0; n2 < 2; ++n2)
                vf[n2] = *(const bf16x8*)&sVt[(n2 * 16 + l15) * 264 + kv0 + ks * 32 + g * 8];
            #pragma unroll
            for (int m = 0; m < 4; ++m) {
                const bf16x8 af = *(const bf16x8*)&sP[w][(m * 16 + l15) * 72 + ks * 32 + g * 8];
                acc[m][0] = MFMA16(af, vf[0], acc[m][0]);
                acc[m][1] = MFMA16(af, vf[1], acc[m][1]);
            }
        }
    }

    // epilogue: O /= l, store to ob [i][j][h][ch]
    #pragma unroll
    for (int m = 0; m < 4; ++m) {
        #pragma unroll
        for (int reg = 0; reg < 4; ++reg) {
            const int q = q0 + m * 16 + g * 4 + reg;
            const float inv = 1.0f / l_run[m][reg];
            const size_t ob_base = ((size_t)(i * 256 + q) * 4 + h) * 32;
            ob[ob_base + l15]      = (unsigned short)f2bf(acc[m][0][reg] * inv);
            ob[ob_base + 16 + l15] = (unsigned short)f2bf(acc[m][1][reg] * inv);
        }
    }
}

// ---------------- Kernel 4: (o*g) @ wo + bo (MFMA) ------------------------
__global__ __launch_bounds__(256, 2) void k_out2(
    const unsigned short* __restrict__ ob, const unsigned short* __restrict__ gb,
    const unsigned short* __restrict__ woT, const float* __restrict__ bo,
    float* __restrict__ out)
{
    __shared__ unsigned short sA[128 * 136];
    __shared__ unsigned short sB[128 * 136];
    const int t = threadIdx.x, w = t >> 6, lane = t & 63;
    const int l15 = lane & 15, g = lane >> 4;
    const int rowBase = blockIdx.x * 128;

    {
        const int r = t >> 1, half = t & 1;
        #pragma unroll
        for (int u = 0; u < 8; ++u) {
            const int c = half * 64 + u * 8;
            const uint4 ov = *(const uint4*)(ob + (size_t)(rowBase + r) * 128 + c);
            const uint4 gv = *(const uint4*)(gb + (size_t)(rowBase + r) * 128 + c);
            uint4 pr;
            pr.x = cvt_pk_bf16(bf2f(ov.x & 0xffffu) * bf2f(gv.x & 0xffffu),
                               bf2f(ov.x >> 16) * bf2f(gv.x >> 16));
            pr.y = cvt_pk_bf16(bf2f(ov.y & 0xffffu) * bf2f(gv.y & 0xffffu),
                               bf2f(ov.y >> 16) * bf2f(gv.y >> 16));
            pr.z = cvt_pk_bf16(bf2f(ov.z & 0xffffu) * bf2f(gv.z & 0xffffu),
                               bf2f(ov.z >> 16) * bf2f(gv.z >> 16));
            pr.w = cvt_pk_bf16(bf2f(ov.w & 0xffffu) * bf2f(gv.w & 0xffffu),
                               bf2f(ov.w >> 16) * bf2f(gv.w >> 16));
            *(uint4*)&sA[r * 136 + c] = pr;
            *(uint4*)&sB[r * 136 + c] = *(const uint4*)(woT + r * 128 + c);
        }
    }
    __syncthreads();

    f32x4 acc[2][8];
    #pragma unroll
    for (int m = 0; m < 2; ++m)
        #pragma unroll
        for (int n = 0; n < 8; ++n) acc[m][n] = (f32x4){0.f, 0.f, 0.f, 0.f};

    bf16x8 af[2][4];
    #pragma unroll
    for (int m = 0; m < 2; ++m)
        #pragma unroll
        for (int ks = 0; ks < 4; ++ks)
            af[m][ks] = *(const bf16x8*)&sA[(w * 32 + m * 16 + l15) * 136 + ks * 32 + g * 8];
    #pragma unroll
    for (int n = 0; n < 8; ++n) {
        #pragma unroll
        for (int ks = 0; ks < 4; ++ks) {
            const bf16x8 bf = *(const bf16x8*)&sB[(n * 16 + l15) * 136 + ks * 32 + g * 8];
            acc[0][n] = MFMA16(af[0][ks], bf, acc[0][n]);
            acc[1][n] = MFMA16(af[1][ks], bf, acc[1][n]);
        }
    }

    // scalar f32 stores (coalesced per 16-lane group)
    float bov[8];
    #pragma unroll
    for (int n = 0; n < 8; ++n) bov[n] = bo[n * 16 + l15];
    #pragma unroll
    for (int m = 0; m < 2; ++m)
        #pragma unroll
        for (int n = 0; n < 8; ++n)
            #pragma unroll
            for (int reg = 0; reg < 4; ++reg) {
                const int row = rowBase + w * 32 + m * 16 + g * 4 + reg;
                out[(size_t)row * 128 + n * 16 + l15] = acc[m][n][reg] + bov[n];
            }
}

extern "C" void kernel_launch(void* const* d_in, const int* in_sizes, int n_in,
                              void* d_out, int out_size, void* d_ws, size_t ws_size,
                              hipStream_t stream) {
    (void)in_sizes; (void)n_in; (void)out_size; (void)ws_size;
    const float* x     = (const float*)d_in[0];
    const float* mask  = (const float*)d_in[1];
    const float* ln_w  = (const float*)d_in[2];
    const float* ln_b  = (const float*)d_in[3];
    const float* w_tri = (const float*)d_in[4];
    const float* wq    = (const float*)d_in[5];
    const float* wk    = (const float*)d_in[6];
    const float* wv    = (const float*)d_in[7];
    const float* wg    = (const float*)d_in[8];
    const float* bg    = (const float*)d_in[9];
    const float* wo    = (const float*)d_in[10];
    const float* bo    = (const float*)d_in[11];
    float* out = (float*)d_out;

    char* ws = (char*)d_ws;
    unsigned int*   xn_u32 = (unsigned int*)ws;
    unsigned short* xn     = (unsigned short*)ws;
    unsigned short* qb     = (unsigned short*)(ws + (16u << 20));
    unsigned short* kb     = (unsigned short*)(ws + (32u << 20));
    unsigned short* vb     = (unsigned short*)(ws + (48u << 20));
    unsigned short* gb     = (unsigned short*)(ws + (64u << 20));
    unsigned short* ob     = (unsigned short*)(ws + (80u << 20));
    unsigned short* triTb  = (unsigned short*)(ws + (96u << 20));
    unsigned short* wT     = (unsigned short*)(ws + (96u << 20) + (512u << 10));

    k_ln_tri<<<NROWS / 4, 256, 0, stream>>>(x, ln_w, ln_b, w_tri, xn_u32, triTb);
    k_prep<<<dim3(5, 8), 128, 0, stream>>>(wq, wk, wv, wg, wo, wT);
    k_proj2<<<dim3(512, 4), 256, 0, stream>>>(xn, wT, bg, qb, kb, vb, gb);
    k_attn2<<<dim3(256, 4), 256, 0, stream>>>(qb, kb, vb, mask, triTb, ob);
    k_out2<<<512, 256, 0, stream>>>(ob, gb, wT + 4 * 16384, bo, out);
}

// Round 4
// 116.585 us; speedup vs baseline: 4.8515x; 1.3873x over previous
//
#include <hip/hip_runtime.h>

// Triangle attention, B=1, I=J=256, C=128, H=4, Ch=32.
// Round 4: swapped-operand attention with per-wave LDS P round-trip
//          (fixes round-3's broken shfl permutation), fused LN+tri+proj.
// ws layout (bytes):
//   q     bf16 [I][H][J][32]         @ 16 MB
//   k     bf16 [I][H][J][32]         @ 32 MB
//   v     bf16 [I][H][J][32]         @ 48 MB
//   g     bf16 [65536][128]          @ 64 MB
//   o     bf16 [I][J][H][32]         @ 80 MB
//   triTb bf16 [H][256(q)][256(kv)]  @ 96 MB        (512 KB)
//   wT    bf16 5 x [128(n)][128(k)]  @ 96 MB+512KB  (wq,wk,wv,wg,wo transposed)

typedef __attribute__((ext_vector_type(4))) float f32x4;
typedef __attribute__((ext_vector_type(8))) short bf16x8;
#define MFMA16(a, b, c) __builtin_amdgcn_mfma_f32_16x16x32_bf16(a, b, c, 0, 0, 0)

__device__ __forceinline__ float bf2f(unsigned int u16) {
    return __uint_as_float(u16 << 16);
}
__device__ __forceinline__ unsigned int f2bf(float f) {
    unsigned int u = __float_as_uint(f);
    return (u + 0x7fffu + ((u >> 16) & 1u)) >> 16;
}
__device__ __forceinline__ unsigned int pack2(float a, float b) {
    return f2bf(a) | (f2bf(b) << 16);
}
__device__ __forceinline__ unsigned int cvt_pk_bf16(float lo, float hi) {
    unsigned int r;
    asm("v_cvt_pk_bf16_f32 %0, %1, %2" : "=v"(r) : "v"(lo), "v"(hi));
    return r;
}

// ---------------- Kernel 0: weight transpose + bf16 cast -----------------
__global__ __launch_bounds__(128) void k_prep(
    const float* __restrict__ wq, const float* __restrict__ wk,
    const float* __restrict__ wv, const float* __restrict__ wg,
    const float* __restrict__ wo, unsigned short* __restrict__ wT)
{
    const int mat = blockIdx.x, k0 = blockIdx.y * 16, t = threadIdx.x;
    const float* W = (mat == 0) ? wq : (mat == 1) ? wk : (mat == 2) ? wv
                     : (mat == 3) ? wg : wo;
    unsigned short* T = wT + mat * 16384;
    float col[16];
    #pragma unroll
    for (int kk = 0; kk < 16; ++kk) col[kk] = W[(k0 + kk) * 128 + t];
    unsigned int pk[8];
    #pragma unroll
    for (int u = 0; u < 8; ++u) pk[u] = pack2(col[2 * u], col[2 * u + 1]);
    *(uint4*)(T + t * 128 + k0)     = make_uint4(pk[0], pk[1], pk[2], pk[3]);
    *(uint4*)(T + t * 128 + k0 + 8) = make_uint4(pk[4], pk[5], pk[6], pk[7]);
}

// -------- Kernel 1: fused LayerNorm + tri bias + q/k/v/g projections ------
__global__ __launch_bounds__(256, 2) void k_lnproj(
    const float* __restrict__ x, const float* __restrict__ ln_w,
    const float* __restrict__ ln_b, const float* __restrict__ w_tri,
    const unsigned short* __restrict__ wT, const float* __restrict__ bg,
    unsigned short* __restrict__ qb, unsigned short* __restrict__ kb,
    unsigned short* __restrict__ vb, unsigned short* __restrict__ gb,
    unsigned short* __restrict__ triTb)
{
    __shared__ unsigned short sA[128 * 136];   // xn tile (bf16)
    __shared__ unsigned short sB[128 * 136];   // weights / epilogue bounce
    __shared__ unsigned short sWt[16 * 136];   // w_tri^T, rows 4..15 zero

    const int t = threadIdx.x, w = t >> 6, lane = t & 63;
    const int l15 = lane & 15, g = lane >> 4;
    const int rowBase = blockIdx.x * 128;

    if (t < 128) {
        const float4 wv = ((const float4*)w_tri)[t];
        sWt[0 * 136 + t] = (unsigned short)f2bf(wv.x);
        sWt[1 * 136 + t] = (unsigned short)f2bf(wv.y);
        sWt[2 * 136 + t] = (unsigned short)f2bf(wv.z);
        sWt[3 * 136 + t] = (unsigned short)f2bf(wv.w);
    } else {
        #pragma unroll
        for (int u = 0; u < 13; ++u) {
            const int idx = (t - 128) + 128 * u;
            if (idx < 12 * 136) sWt[4 * 136 + idx] = 0;
        }
    }

    // ---- LayerNorm: 2 threads per row ----
    {
        const int r = t >> 1, half = t & 1;
        const float* xr = x + (size_t)(rowBase + r) * 128 + half * 64;
        float v[64];
        float s1 = 0.0f, s2 = 0.0f;
        #pragma unroll
        for (int u = 0; u < 16; ++u) {
            const float4 q4 = ((const float4*)xr)[u];
            v[4*u] = q4.x; v[4*u+1] = q4.y; v[4*u+2] = q4.z; v[4*u+3] = q4.w;
            s1 += q4.x + q4.y + q4.z + q4.w;
            s2 += q4.x*q4.x + q4.y*q4.y + q4.z*q4.z + q4.w*q4.w;
        }
        s1 += __shfl_xor(s1, 1);
        s2 += __shfl_xor(s2, 1);
        const float mu = s1 * (1.0f / 128.0f);
        const float rs = rsqrtf(s2 * (1.0f / 128.0f) - mu * mu + 1e-5f);
        const float4* lw = (const float4*)(ln_w + half * 64);
        const float4* lb = (const float4*)(ln_b + half * 64);
        #pragma unroll
        for (int u = 0; u < 16; ++u) {
            const float4 w4 = lw[u], b4 = lb[u];
            v[4*u]   = (v[4*u]   - mu) * rs * w4.x + b4.x;
            v[4*u+1] = (v[4*u+1] - mu) * rs * w4.y + b4.y;
            v[4*u+2] = (v[4*u+2] - mu) * rs * w4.z + b4.z;
            v[4*u+3] = (v[4*u+3] - mu) * rs * w4.w + b4.w;
        }
        #pragma unroll
        for (int u = 0; u < 8; ++u) {
            uint4 pk;
            pk.x = pack2(v[8*u],   v[8*u+1]);
            pk.y = pack2(v[8*u+2], v[8*u+3]);
            pk.z = pack2(v[8*u+4], v[8*u+5]);
            pk.w = pack2(v[8*u+6], v[8*u+7]);
            *(uint4*)&sA[r * 136 + half * 64 + u * 8] = pk;
        }
    }
    __syncthreads();

    bf16x8 af[2][4];
    #pragma unroll
    for (int m = 0; m < 2; ++m)
        #pragma unroll
        for (int ks = 0; ks < 4; ++ks)
            af[m][ks] = *(const bf16x8*)&sA[(w * 32 + m * 16 + l15) * 136 + ks * 32 + g * 8];

    // ---- tri bias via MFMA ----
    #pragma unroll
    for (int m = 0; m < 2; ++m) {
        f32x4 tc = (f32x4){0.f, 0.f, 0.f, 0.f};
        #pragma unroll
        for (int ks = 0; ks < 4; ++ks) {
            const bf16x8 bfw = *(const bf16x8*)&sWt[l15 * 136 + ks * 32 + g * 8];
            tc = MFMA16(af[m][ks], bfw, tc);
        }
        if (l15 < 4) {
            #pragma unroll
            for (int reg = 0; reg < 4; ++reg) {
                const int gr = rowBase + w * 32 + m * 16 + 4 * g + reg;
                triTb[l15 * 65536 + gr] = (unsigned short)f2bf(tc[reg]);
            }
        }
    }

    // ---- 4 projection GEMMs ----
    const int r2 = t >> 1, half2 = t & 1;
    for (int mat = 0; mat < 4; ++mat) {
        {
            const unsigned short* Wm = wT + mat * 16384 + r2 * 128 + half2 * 64;
            #pragma unroll
            for (int u = 0; u < 8; ++u)
                *(uint4*)&sB[r2 * 136 + half2 * 64 + u * 8] = *(const uint4*)(Wm + u * 8);
        }
        __syncthreads();

        f32x4 acc[2][8];
        #pragma unroll
        for (int m = 0; m < 2; ++m)
            #pragma unroll
            for (int n = 0; n < 8; ++n) acc[m][n] = (f32x4){0.f, 0.f, 0.f, 0.f};
        #pragma unroll
        for (int n = 0; n < 8; ++n)
            #pragma unroll
            for (int ks = 0; ks < 4; ++ks) {
                const bf16x8 bf = *(const bf16x8*)&sB[(n * 16 + l15) * 136 + ks * 32 + g * 8];
                acc[0][n] = MFMA16(af[0][ks], bf, acc[0][n]);
                acc[1][n] = MFMA16(af[1][ks], bf, acc[1][n]);
            }
        __syncthreads();

        float bgv[8];
        if (mat == 3) {
            #pragma unroll
            for (int n = 0; n < 8; ++n) bgv[n] = bg[n * 16 + l15];
        }
        const float scl = (mat == 0) ? 0.17677669529663689f : 1.0f;
        #pragma unroll
        for (int m = 0; m < 2; ++m)
            #pragma unroll
            for (int n = 0; n < 8; ++n) {
                float vv[4];
                #pragma unroll
                for (int reg = 0; reg < 4; ++reg) {
                    float z = acc[m][n][reg];
                    if (mat == 3) z = 1.0f / (1.0f + __expf(-(z + bgv[n])));
                    else z *= scl;
                    vv[reg] = z;
                }
                const unsigned int a01 = cvt_pk_bf16(vv[0], vv[1]);
                const unsigned int a23 = cvt_pk_bf16(vv[2], vv[3]);
                const int qr = w * 32 + m * 16 + g * 4;
                const int col = n * 16 + l15;
                sB[qr * 136 + col]       = (unsigned short)a01;
                sB[(qr + 1) * 136 + col] = (unsigned short)(a01 >> 16);
                sB[(qr + 2) * 136 + col] = (unsigned short)a23;
                sB[(qr + 3) * 136 + col] = (unsigned short)(a23 >> 16);
            }
        __syncthreads();

        const int row = rowBase + r2;
        if (mat < 3) {
            unsigned short* dst = (mat == 0) ? qb : (mat == 1) ? kb : vb;
            const int i = row >> 8, j = row & 255;
            #pragma unroll
            for (int u = 0; u < 8; ++u) {
                const int c0 = half2 * 64 + u * 8;
                const int hh = c0 >> 5, ch = c0 & 31;
                *(uint4*)(dst + (((size_t)(i * 4 + hh)) * 256 + j) * 32 + ch) =
                    *(const uint4*)&sB[r2 * 136 + c0];
            }
        } else {
            #pragma unroll
            for (int u = 0; u < 8; ++u) {
                const int c0 = half2 * 64 + u * 8;
                *(uint4*)(gb + (size_t)row * 128 + c0) = *(const uint4*)&sB[r2 * 136 + c0];
            }
        }
        __syncthreads();
    }
}

// ---------------- Kernel 2: attention, swapped operands -------------------
// Sᵀ via mfma(K,Q): lane(l15,g) holds P[q=l15-col][kv=4g+reg per n-tile].
// P redistributed for PV through per-wave LDS sP[64 q][72 kv-shorts].
__global__ __launch_bounds__(256, 2) void k_attn4(
    const unsigned short* __restrict__ qb, const unsigned short* __restrict__ kb,
    const unsigned short* __restrict__ vb, const float* __restrict__ mask,
    const unsigned short* __restrict__ triTb, unsigned short* __restrict__ ob)
{
    __shared__ unsigned short sK[256 * 40];    // [kv][c]
    __shared__ unsigned short sVt[32 * 264];   // [c][kv]
    __shared__ unsigned short sP[4][64 * 72];  // per-wave [q][kv], stride 144B
    __shared__ float sM[256];

    const int i = blockIdx.x, h = blockIdx.y, t = threadIdx.x;
    const int w = t >> 6, lane = t & 63, l15 = lane & 15, g = lane >> 4;
    const size_t base = (size_t)(i * 4 + h) * 8192;

    {
        const uint4* ks = (const uint4*)(kb + base + t * 32);
        uint4 k0 = ks[0], k1 = ks[1], k2 = ks[2], k3 = ks[3];
        *(uint4*)&sK[t * 40]      = k0;
        *(uint4*)&sK[t * 40 + 8]  = k1;
        *(uint4*)&sK[t * 40 + 16] = k2;
        *(uint4*)&sK[t * 40 + 24] = k3;
        const uint4* vs = (const uint4*)(vb + base + t * 32);
        uint4 v0 = vs[0], v1 = vs[1], v2 = vs[2], v3 = vs[3];
        const unsigned int vw[16] = {v0.x, v0.y, v0.z, v0.w, v1.x, v1.y, v1.z, v1.w,
                                     v2.x, v2.y, v2.z, v2.w, v3.x, v3.y, v3.z, v3.w};
        #pragma unroll
        for (int u = 0; u < 16; ++u) {
            sVt[(2 * u) * 264 + t]     = (unsigned short)(vw[u] & 0xffffu);
            sVt[(2 * u + 1) * 264 + t] = (unsigned short)(vw[u] >> 16);
        }
        sM[t] = 1.0e9f * (mask[i * 256 + t] - 1.0f);
    }

    const int q0 = w * 64;
    bf16x8 qf[4];
    #pragma unroll
    for (int m = 0; m < 4; ++m)
        qf[m] = *(const bf16x8*)(qb + base + (size_t)(q0 + m * 16 + l15) * 32 + g * 8);
    __syncthreads();

    f32x4 acc[4][2];
    float m_run[4], l_run[4];
    #pragma unroll
    for (int m = 0; m < 4; ++m) {
        acc[m][0] = (f32x4){0.f, 0.f, 0.f, 0.f};
        acc[m][1] = (f32x4){0.f, 0.f, 0.f, 0.f};
        m_run[m] = -1.0e30f;
        l_run[m] = 0.0f;
    }

    unsigned short* sPw = &sP[w][0];
    const unsigned short* triQ = triTb + h * 65536;
    const f32x4 zero = (f32x4){0.f, 0.f, 0.f, 0.f};

    for (int kt = 0; kt < 4; ++kt) {
        const int kv0 = kt * 64;
        bf16x8 kf[4];
        #pragma unroll
        for (int n = 0; n < 4; ++n)
            kf[n] = *(const bf16x8*)&sK[(kv0 + n * 16 + l15) * 40 + g * 8];

        float fm[4];
        #pragma unroll
        for (int m = 0; m < 4; ++m) {
            // Sᵀ tile: row kv = kv0+16n+4g+reg, col q = q0+16m+l15
            f32x4 p[4];
            #pragma unroll
            for (int n = 0; n < 4; ++n)
                p[n] = MFMA16(kf[n], qf[m], zero);

            const unsigned short* tq = triQ + (q0 + m * 16 + l15) * 256 + kv0;
            #pragma unroll
            for (int n = 0; n < 4; ++n) {
                const float4 mk = *(const float4*)&sM[kv0 + n * 16 + g * 4];
                const ushort4 tv = *(const ushort4*)(tq + n * 16 + g * 4);
                p[n][0] += mk.x + bf2f(tv.x);
                p[n][1] += mk.y + bf2f(tv.y);
                p[n][2] += mk.z + bf2f(tv.z);
                p[n][3] += mk.w + bf2f(tv.w);
            }
            float mx = p[0][0];
            #pragma unroll
            for (int n = 0; n < 4; ++n)
                #pragma unroll
                for (int reg = 0; reg < 4; ++reg) mx = fmaxf(mx, p[n][reg]);
            mx = fmaxf(mx, __shfl_xor(mx, 16));
            mx = fmaxf(mx, __shfl_xor(mx, 32));
            const float mnew = fmaxf(m_run[m], mx);
            const float f = __expf(m_run[m] - mnew);
            m_run[m] = mnew;
            fm[m] = f;
            float sum = 0.0f;
            #pragma unroll
            for (int n = 0; n < 4; ++n)
                #pragma unroll
                for (int reg = 0; reg < 4; ++reg) {
                    p[n][reg] = __expf(p[n][reg] - mnew);
                    sum += p[n][reg];
                }
            sum += __shfl_xor(sum, 16);
            sum += __shfl_xor(sum, 32);
            l_run[m] = l_run[m] * f + sum;
            // store P row to per-wave LDS: sP[q_local=16m+l15][16n+4g .. +3]
            #pragma unroll
            for (int n = 0; n < 4; ++n) {
                const unsigned int a01 = cvt_pk_bf16(p[n][0], p[n][1]);
                const unsigned int a23 = cvt_pk_bf16(p[n][2], p[n][3]);
                *(uint2*)&sPw[(m * 16 + l15) * 72 + n * 16 + g * 4] = make_uint2(a01, a23);
            }
        }
        #pragma unroll
        for (int m = 0; m < 4; ++m)
            #pragma unroll
            for (int n2 = 0; n2 < 2; ++n2)
                #pragma unroll
                for (int reg = 0; reg < 4; ++reg) acc[m][n2][reg] *= fm[m];

        // PV: Oᵀ += Vᵀ · Pᵀ ; B-frag = ds_read_b128 from own wave's sP
        #pragma unroll
        for (int ks = 0; ks < 2; ++ks) {
            const bf16x8 vf0 = *(const bf16x8*)&sVt[l15 * 264 + kv0 + ks * 32 + g * 8];
            const bf16x8 vf1 = *(const bf16x8*)&sVt[(16 + l15) * 264 + kv0 + ks * 32 + g * 8];
            #pragma unroll
            for (int m = 0; m < 4; ++m) {
                const bf16x8 pb = *(const bf16x8*)&sPw[(m * 16 + l15) * 72 + ks * 32 + g * 8];
                acc[m][0] = MFMA16(vf0, pb, acc[m][0]);
                acc[m][1] = MFMA16(vf1, pb, acc[m][1]);
            }
        }
    }

    // epilogue: Oᵀ[ch][q] -> ob[i][q][h][ch]
    #pragma unroll
    for (int m = 0; m < 4; ++m) {
        const float inv = 1.0f / l_run[m];
        const int q = q0 + m * 16 + l15;
        unsigned short* op = ob + (((size_t)(i * 256 + q)) * 4 + h) * 32;
        #pragma unroll
        for (int n2 = 0; n2 < 2; ++n2) {
            const unsigned int a01 = cvt_pk_bf16(acc[m][n2][0] * inv, acc[m][n2][1] * inv);
            const unsigned int a23 = cvt_pk_bf16(acc[m][n2][2] * inv, acc[m][n2][3] * inv);
            *(uint2*)(op + n2 * 16 + g * 4) = make_uint2(a01, a23);
        }
    }
}

// ---------------- Kernel 3: (o*g) @ wo + bo (MFMA) ------------------------
__global__ __launch_bounds__(256, 2) void k_out2(
    const unsigned short* __restrict__ ob, const unsigned short* __restrict__ gb,
    const unsigned short* __restrict__ woT, const float* __restrict__ bo,
    float* __restrict__ out)
{
    __shared__ unsigned short sA[128 * 136];
    __shared__ unsigned short sB[128 * 136];
    const int t = threadIdx.x, w = t >> 6, lane = t & 63;
    const int l15 = lane & 15, g = lane >> 4;
    const int rowBase = blockIdx.x * 128;

    {
        const int r = t >> 1, half = t & 1;
        #pragma unroll
        for (int u = 0; u < 8; ++u) {
            const int c = half * 64 + u * 8;
            const uint4 ov = *(const uint4*)(ob + (size_t)(rowBase + r) * 128 + c);
            const uint4 gv = *(const uint4*)(gb + (size_t)(rowBase + r) * 128 + c);
            uint4 pr;
            pr.x = cvt_pk_bf16(bf2f(ov.x & 0xffffu) * bf2f(gv.x & 0xffffu),
                               bf2f(ov.x >> 16) * bf2f(gv.x >> 16));
            pr.y = cvt_pk_bf16(bf2f(ov.y & 0xffffu) * bf2f(gv.y & 0xffffu),
                               bf2f(ov.y >> 16) * bf2f(gv.y >> 16));
            pr.z = cvt_pk_bf16(bf2f(ov.z & 0xffffu) * bf2f(gv.z & 0xffffu),
                               bf2f(ov.z >> 16) * bf2f(gv.z >> 16));
            pr.w = cvt_pk_bf16(bf2f(ov.w & 0xffffu) * bf2f(gv.w & 0xffffu),
                               bf2f(ov.w >> 16) * bf2f(gv.w >> 16));
            *(uint4*)&sA[r * 136 + c] = pr;
            *(uint4*)&sB[r * 136 + c] = *(const uint4*)(woT + r * 128 + c);
        }
    }
    __syncthreads();

    f32x4 acc[2][8];
    #pragma unroll
    for (int m = 0; m < 2; ++m)
        #pragma unroll
        for (int n = 0; n < 8; ++n) acc[m][n] = (f32x4){0.f, 0.f, 0.f, 0.f};

    bf16x8 af[2][4];
    #pragma unroll
    for (int m = 0; m < 2; ++m)
        #pragma unroll
        for (int ks = 0; ks < 4; ++ks)
            af[m][ks] = *(const bf16x8*)&sA[(w * 32 + m * 16 + l15) * 136 + ks * 32 + g * 8];
    #pragma unroll
    for (int n = 0; n < 8; ++n) {
        #pragma unroll
        for (int ks = 0; ks < 4; ++ks) {
            const bf16x8 bf = *(const bf16x8*)&sB[(n * 16 + l15) * 136 + ks * 32 + g * 8];
            acc[0][n] = MFMA16(af[0][ks], bf, acc[0][n]);
            acc[1][n] = MFMA16(af[1][ks], bf, acc[1][n]);
        }
    }

    float bov[8];
    #pragma unroll
    for (int n = 0; n < 8; ++n) bov[n] = bo[n * 16 + l15];
    #pragma unroll
    for (int m = 0; m < 2; ++m)
        #pragma unroll
        for (int n = 0; n < 8; ++n)
            #pragma unroll
            for (int reg = 0; reg < 4; ++reg) {
                const int row = rowBase + w * 32 + m * 16 + g * 4 + reg;
                out[(size_t)row * 128 + n * 16 + l15] = acc[m][n][reg] + bov[n];
            }
}

extern "C" void kernel_launch(void* const* d_in, const int* in_sizes, int n_in,
                              void* d_out, int out_size, void* d_ws, size_t ws_size,
                              hipStream_t stream) {
    (void)in_sizes; (void)n_in; (void)out_size; (void)ws_size;
    const float* x     = (const float*)d_in[0];
    const float* mask  = (const float*)d_in[1];
    const float* ln_w  = (const float*)d_in[2];
    const float* ln_b  = (const float*)d_in[3];
    const float* w_tri = (const float*)d_in[4];
    const float* wq    = (const float*)d_in[5];
    const float* wk    = (const float*)d_in[6];
    const float* wv    = (const float*)d_in[7];
    const float* wg    = (const float*)d_in[8];
    const float* bg    = (const float*)d_in[9];
    const float* wo    = (const float*)d_in[10];
    const float* bo    = (const float*)d_in[11];
    float* out = (float*)d_out;

    char* ws = (char*)d_ws;
    unsigned short* qb     = (unsigned short*)(ws + (16u << 20));
    unsigned short* kb     = (unsigned short*)(ws + (32u << 20));
    unsigned short* vb     = (unsigned short*)(ws + (48u << 20));
    unsigned short* gb     = (unsigned short*)(ws + (64u << 20));
    unsigned short* ob     = (unsigned short*)(ws + (80u << 20));
    unsigned short* triTb  = (unsigned short*)(ws + (96u << 20));
    unsigned short* wT     = (unsigned short*)(ws + (96u << 20) + (512u << 10));

    k_prep<<<dim3(5, 8), 128, 0, stream>>>(wq, wk, wv, wg, wo, wT);
    k_lnproj<<<512, 256, 0, stream>>>(x, ln_w, ln_b, w_tri, wT, bg,
                                      qb, kb, vb, gb, triTb);
    k_attn4<<<dim3(256, 4), 256, 0, stream>>>(qb, kb, vb, mask, triTb, ob);
    k_out2<<<512, 256, 0, stream>>>(ob, gb, wT + 4 * 16384, bo, out);
}